// Round 2
// baseline (277.061 us; speedup 1.0000x reference)
//
#include <hip/hip_runtime.h>

#define EPSF 1e-5f

// Kernel 1: one block per (b,n) pair. Reduce the 64x64 heatmap tile to the
// 7 raw moments, then closed-form 2x2 eigendecomposition + loss epilogue.
// Writes one float per pair: 0.5*sum_j(scale_j^2) + (|l0|+|l1|).
__global__ __launch_bounds__(256) void star_pair_kernel(
    const float* __restrict__ heatmap,
    const float* __restrict__ gt,
    float* __restrict__ pair_out)
{
    const int pair = blockIdx.x;
    const float* hp = heatmap + (size_t)pair * 4096;
    const int t = threadIdx.x;

    const float cgrid = 2.0f / 63.0f;

    float s0 = 0.f, s1 = 0.f, s2 = 0.f, s3 = 0.f, s4 = 0.f, s5 = 0.f, s6 = 0.f;

    // 4096 floats = 1024 float4; 256 threads * 4 float4 each, coalesced.
    #pragma unroll
    for (int i = 0; i < 4; ++i) {
        const int f = t + i * 256;                 // float4 index [0,1024)
        const float4 v = reinterpret_cast<const float4*>(hp)[f];
        const int y = f >> 4;                      // 16 float4 per 64-wide row
        const int x0 = (f & 15) << 2;
        const float yf = fmaf((float)y, cgrid, -1.0f);
        const float a[4] = {v.x, v.y, v.z, v.w};
        #pragma unroll
        for (int k = 0; k < 4; ++k) {
            const float xf = fmaf((float)(x0 + k), cgrid, -1.0f);
            const float av = a[k];
            s0 += av;
            s6 = fmaf(av, av, s6);
            s1 = fmaf(av, xf, s1);
            s2 = fmaf(av, yf, s2);
            const float ax = av * xf;
            s3 = fmaf(ax, xf, s3);
            s4 = fmaf(ax, yf, s4);
            const float ay = av * yf;
            s5 = fmaf(ay, yf, s5);
        }
    }

    // wave64 shuffle reduction of the 7 sums
    #pragma unroll
    for (int off = 32; off >= 1; off >>= 1) {
        s0 += __shfl_down(s0, off);
        s1 += __shfl_down(s1, off);
        s2 += __shfl_down(s2, off);
        s3 += __shfl_down(s3, off);
        s4 += __shfl_down(s4, off);
        s5 += __shfl_down(s5, off);
        s6 += __shfl_down(s6, off);
    }

    __shared__ float red[4][7];
    const int wave = t >> 6;
    const int lane = t & 63;
    if (lane == 0) {
        red[wave][0] = s0; red[wave][1] = s1; red[wave][2] = s2;
        red[wave][3] = s3; red[wave][4] = s4; red[wave][5] = s5;
        red[wave][6] = s6;
    }
    __syncthreads();

    if (t == 0) {
        s0 = red[0][0] + red[1][0] + red[2][0] + red[3][0];
        s1 = red[0][1] + red[1][1] + red[2][1] + red[3][1];
        s2 = red[0][2] + red[1][2] + red[2][2] + red[3][2];
        s3 = red[0][3] + red[1][3] + red[2][3] + red[3][3];
        s4 = red[0][4] + red[1][4] + red[2][4] + red[3][4];
        s5 = red[0][5] + red[1][5] + red[2][5] + red[3][5];
        s6 = red[0][6] + red[1][6] + red[2][6] + red[3][6];

        // normalization: hm = a / max(sum(a), 1e-6)
        const float S = s0 > 1e-6f ? s0 : 1e-6f;
        const float inv = 1.0f / S;
        const float T  = s0 * inv;           // sum(hm)  (== 1 for this data)
        const float mx = s1 * inv;           // sum(hm*x)
        const float my = s2 * inv;           // sum(hm*y)
        const float Exx = s3 * inv;
        const float Exy = s4 * inv;
        const float Eyy = s5 * inv;
        const float V2raw = s6 * inv * inv;  // sum(hm^2)

        // unbiased weighted covariance:
        // sum hm*(x-mx)^2 = Exx - mx^2*(2-T), etc. (T==1 for this data)
        const float c2mT = 2.0f - T;
        float c00 = Exx - mx * mx * c2mT;
        float c01 = Exy - mx * my * c2mT;
        float c11 = Eyy - my * my * c2mT;
        const float V1 = T + EPSF;
        const float denom = V1 - (V2raw + EPSF) / V1;
        const float idn = 1.0f / denom;
        c00 *= idn; c01 *= idn; c11 *= idn;

        // 2x2 symmetric eig, ascending: lambda = mmid -/+ r
        const float mmid = 0.5f * (c00 + c11);
        const float h = 0.5f * (c00 - c11);
        const float r = sqrtf(h * h + c01 * c01);
        const float l0 = mmid - r;           // smaller
        const float l1 = mmid + r;           // larger
        // eigenvector for l1: (h + r, c01); eigenbasis as reflection (V=V^T)
        float vx = h + r, vy = c01;
        const float nn = vx * vx + vy * vy;
        float cc, ssn;
        if (nn > 1e-30f) {
            const float rin = rsqrtf(nn);
            cc = vx * rin; ssn = vy * rin;
        } else {
            cc = 0.0f; ssn = 1.0f;           // c01==0, c00<=c11 -> v1=(0,1)
        }

        // pts = groundtruth - means; projections onto eigenbasis
        const float px = gt[2 * pair]     - mx;
        const float py = gt[2 * pair + 1] - my;
        const float r1 = cc * px + ssn * py;     // onto v(l1)
        const float r0 = -ssn * px + cc * py;    // onto v(l0)

        // loss_trans contribution: mean over [b,n,2] -> 0.5*ssum per pair
        const float ssum = r0 * r0 / (l0 + EPSF) + r1 * r1 / (l1 + EPSF);
        const float esum = fabsf(l0) + fabsf(l1);
        pair_out[pair] = 0.5f * ssum + esum;     // per-pair contribution
    }
}

// Kernel 2: reduce 12544 per-pair contributions -> scalar loss.
__global__ __launch_bounds__(1024) void star_reduce_kernel(
    const float* __restrict__ pair_out,
    float* __restrict__ out,
    int n, float inv_n)
{
    float s = 0.f;
    for (int i = threadIdx.x; i < n; i += 1024) s += pair_out[i];
    #pragma unroll
    for (int off = 32; off >= 1; off >>= 1) s += __shfl_down(s, off);
    __shared__ float red[16];
    const int wave = threadIdx.x >> 6;
    const int lane = threadIdx.x & 63;
    if (lane == 0) red[wave] = s;
    __syncthreads();
    if (threadIdx.x == 0) {
        float tot = 0.f;
        #pragma unroll
        for (int w = 0; w < 16; ++w) tot += red[w];
        out[0] = tot * inv_n;
    }
}

extern "C" void kernel_launch(void* const* d_in, const int* in_sizes, int n_in,
                              void* d_out, int out_size, void* d_ws, size_t ws_size,
                              hipStream_t stream) {
    const float* heatmap = (const float*)d_in[0];
    const float* gt      = (const float*)d_in[1];
    float* out = (float*)d_out;
    float* pair_out = (float*)d_ws;

    const int npairs = in_sizes[1] / 2;   // 128*98 = 12544

    star_pair_kernel<<<npairs, 256, 0, stream>>>(heatmap, gt, pair_out);
    star_reduce_kernel<<<1, 1024, 0, stream>>>(pair_out, out, npairs,
                                               1.0f / (float)npairs);
}